// Round 1
// baseline (227.806 us; speedup 1.0000x reference)
//
#include <hip/hip_runtime.h>
#include <math.h>

// N=768 nodes, F=64 feat, DE=32 edge-attr, hidden=64, adjacency ~5% dense.
// Sparse strategy: only ~29.5k edges matter (A is binary); compute per-edge
// MLP only for actual edges. One block per node i; 4 waves cooperate per edge;
// MLP weights held in registers (lane -> (out-channel, d-slice)).

#define NN 768
#define FF 64
#define DE 32
#define HH 64

__global__ __launch_bounds__(256, 4) void edgeconv_kernel(
    const float* __restrict__ A, const float* __restrict__ x,
    const float* __restrict__ e, const float* __restrict__ Wa,
    const float* __restrict__ ba, const float* __restrict__ Wb,
    const float* __restrict__ bb, float* __restrict__ xout)
{
  const int i = blockIdx.x;
  const int tid = threadIdx.x;
  const int lane = tid & 63;
  const int wv = tid >> 6;              // wave 0..3
  const int slice = lane >> 4;          // d-slice 0..3
  const int k = wv * 16 + (lane & 15);  // output channel 0..63

  __shared__ int s_cnt;
  __shared__ int s_j[NN];
  __shared__ float s_a[NN];
  __shared__ __align__(16) float s_feat[160];  // [x_i | x_j - x_i | e_ij]
  __shared__ __align__(16) float s_h1[64];

  if (tid == 0) s_cnt = 0;
  __syncthreads();

  // scan adjacency row -> neighbor list in LDS
  for (int j = tid; j < NN; j += 256) {
    float a = A[i * NN + j];
    if (a != 0.0f) {
      int p = atomicAdd(&s_cnt, 1);
      s_j[p] = j;
      s_a[p] = a;
    }
  }
  if (tid < FF) s_feat[tid] = x[i * FF + tid];  // x_i part, constant per block
  __syncthreads();
  const int cnt = s_cnt;

  // Load this lane's weight slices into registers.
  // w1[t] = Wa[d][k] for d = slice*40 + t   (Wa is [160][64] row-major)
  float w1[40];
#pragma unroll
  for (int t = 0; t < 40; ++t) w1[t] = Wa[(slice * 40 + t) * HH + k];
  // w2[t] = Wb[c][k] for c = slice*16 + t   (Wb is [64][64] row-major)
  float w2[16];
#pragma unroll
  for (int t = 0; t < 16; ++t) w2[t] = Wb[(slice * 16 + t) * HH + k];
  const float bias1 = ba[k];
  const float bias2 = bb[k];

  float acc = 0.0f;

  for (int t = 0; t < cnt; ++t) {
    const int j = s_j[t];
    // stage feat[64:160]: x_j - x_i and e_ij
    if (tid < FF) {
      s_feat[FF + tid] = x[j * FF + tid] - s_feat[tid];
    } else if (tid < FF + DE) {
      s_feat[2 * FF + (tid - FF)] = e[((size_t)i * NN + j) * DE + (tid - FF)];
    }
    __syncthreads();

    // h1 partial over this lane's d-slice (40 d's, float4-vectorized broadcast)
    float p = 0.0f;
    const float4* f4 = (const float4*)(s_feat + slice * 40);
#pragma unroll
    for (int u = 0; u < 10; ++u) {
      float4 f = f4[u];
      p = fmaf(f.x, w1[4 * u + 0], p);
      p = fmaf(f.y, w1[4 * u + 1], p);
      p = fmaf(f.z, w1[4 * u + 2], p);
      p = fmaf(f.w, w1[4 * u + 3], p);
    }
    p += __shfl_down(p, 32);
    p += __shfl_down(p, 16);
    if (lane < 16) s_h1[k] = fmaxf(p + bias1, 0.0f);
    __syncthreads();

    // h2 partial over this lane's c-slice (16 c's)
    float q = 0.0f;
    const float4* h4 = (const float4*)(s_h1 + slice * 16);
#pragma unroll
    for (int u = 0; u < 4; ++u) {
      float4 h = h4[u];
      q = fmaf(h.x, w2[4 * u + 0], q);
      q = fmaf(h.y, w2[4 * u + 1], q);
      q = fmaf(h.z, w2[4 * u + 2], q);
      q = fmaf(h.w, w2[4 * u + 3], q);
    }
    q += __shfl_down(q, 32);
    q += __shfl_down(q, 16);
    if (lane < 16) acc = fmaf(s_a[t], fmaxf(q + bias2, 0.0f), acc);
    __syncthreads();  // protect s_feat/s_h1 for next iteration
  }

  if (lane < 16) xout[i * HH + k] = acc;
}

// x2[768,64] -> relu(x2 @ W3[64,128] + b3) -> sigmoid(@ W4[128,1] + b4)
__global__ __launch_bounds__(128) void final_kernel(
    const float* __restrict__ x2, const float* __restrict__ W3,
    const float* __restrict__ b3, const float* __restrict__ W4,
    const float* __restrict__ b4, float* __restrict__ out)
{
  const int i = blockIdx.x;
  const int t = threadIdx.x;  // 0..127
  const int lane = t & 63;
  const int wv = t >> 6;
  __shared__ float sx[64];
  __shared__ float s_red[2];
  if (t < 64) sx[t] = x2[i * 64 + t];
  __syncthreads();
  float p = b3[t];
#pragma unroll
  for (int c = 0; c < 64; ++c) p = fmaf(sx[c], W3[c * 128 + t], p);
  p = fmaxf(p, 0.0f);
  float v = p * W4[t];
  v += __shfl_down(v, 32);
  v += __shfl_down(v, 16);
  v += __shfl_down(v, 8);
  v += __shfl_down(v, 4);
  v += __shfl_down(v, 2);
  v += __shfl_down(v, 1);
  if (lane == 0) s_red[wv] = v;
  __syncthreads();
  if (t == 0) {
    float z = s_red[0] + s_red[1] + b4[0];
    out[i] = 1.0f / (1.0f + expf(-z));
  }
}

extern "C" void kernel_launch(void* const* d_in, const int* in_sizes, int n_in,
                              void* d_out, int out_size, void* d_ws, size_t ws_size,
                              hipStream_t stream) {
  const float* A   = (const float*)d_in[0];
  const float* x   = (const float*)d_in[1];
  const float* e   = (const float*)d_in[2];
  const float* W1a = (const float*)d_in[3];
  const float* b1a = (const float*)d_in[4];
  const float* W1b = (const float*)d_in[5];
  const float* b1b = (const float*)d_in[6];
  const float* W2a = (const float*)d_in[7];
  const float* b2a = (const float*)d_in[8];
  const float* W2b = (const float*)d_in[9];
  const float* b2b = (const float*)d_in[10];
  const float* W3  = (const float*)d_in[11];
  const float* b3  = (const float*)d_in[12];
  const float* W4  = (const float*)d_in[13];
  const float* b4  = (const float*)d_in[14];
  float* out = (float*)d_out;

  float* x1 = (float*)d_ws;            // [768,64]
  float* x2 = x1 + NN * HH;            // [768,64]

  edgeconv_kernel<<<NN, 256, 0, stream>>>(A, x,  e, W1a, b1a, W1b, b1b, x1);
  edgeconv_kernel<<<NN, 256, 0, stream>>>(A, x1, e, W2a, b2a, W2b, b2b, x2);
  final_kernel<<<NN, 128, 0, stream>>>(x2, W3, b3, W4, b4, out);
}

// Round 2
// 191.072 us; speedup vs baseline: 1.1923x; 1.1923x over previous
//
#include <hip/hip_runtime.h>
#include <math.h>

// Sparse EdgeConvE: ~29.5k real edges out of 768^2. One block per node i.
// Batch-8 edges per barrier trio, register-prefetch next batch's loads,
// and hoist the per-block-constant x_i contribution out of the edge loop:
//   sum(x_i*Wa[0:64] + (x_j-x_i)*Wa[64:128] + e*Wa[128:160])
// = [x_i*(Wa[0:64]-Wa[64:128])]  (per-block const c_xi)
// + x_j*Wa[64:128] + e*Wa[128:160]   (per-edge, 96 dims)

#define NN 768
#define FF 64
#define DE 32
#define HH 64
#define EB 8          // edge batch size
#define PD 96         // per-edge feature dims after hoist (64 xj + 32 e)

__global__ __launch_bounds__(256, 4) void edgeconv_kernel(
    const float* __restrict__ A, const float* __restrict__ x,
    const float* __restrict__ e, const float* __restrict__ Wa,
    const float* __restrict__ ba, const float* __restrict__ Wb,
    const float* __restrict__ bb, float* __restrict__ xout)
{
  const int i = blockIdx.x;
  const int tid = threadIdx.x;
  const int lane = tid & 63;
  const int wv = tid >> 6;              // wave 0..3
  const int slice = lane >> 4;          // 0..3
  const int k = wv * 16 + (lane & 15);  // output channel 0..63

  __shared__ int s_cnt;
  __shared__ int s_j[NN];
  __shared__ float s_a[NN];
  __shared__ __align__(16) float s_feat[EB * PD];  // [xj(64) | e(32)] per edge
  __shared__ __align__(16) float s_h1[EB * HH];
  __shared__ __align__(16) float s_xi[FF];
  __shared__ float s_cxi[HH];

  if (tid == 0) s_cnt = 0;
  __syncthreads();

  // ---- scan adjacency row -> LDS neighbor list ----
  for (int j = tid; j < NN; j += 256) {
    float a = A[i * NN + j];
    if (a != 0.0f) {
      int p = atomicAdd(&s_cnt, 1);
      s_j[p] = j;
      s_a[p] = a;
    }
  }
  if (tid < FF / 4) ((float4*)s_xi)[tid] = ((const float4*)(x + i * FF))[tid];
  __syncthreads();

  const int cnt = s_cnt;
  if (cnt == 0) {
    if (lane < 16) xout[i * HH + k] = 0.0f;
    return;
  }
  const int cnt_pad = (cnt + EB - 1) & ~(EB - 1);
  // pad neighbor list with zero-weight copies of edge 0
  if (tid >= cnt && tid < cnt_pad) { s_j[tid] = s_j[0]; s_a[tid] = 0.0f; }

  // ---- per-lane register weights ----
  // layer1 per-edge weights: dim d of [xj|e] -> Wa[(64+d)][k], d = slice*24+t
  float w1[24];
#pragma unroll
  for (int t = 0; t < 24; ++t) w1[t] = Wa[(size_t)(64 + slice * 24 + t) * HH + k];
  // layer2: Wb[c][k], c = slice*16+t
  float w2[16];
#pragma unroll
  for (int t = 0; t < 16; ++t) w2[t] = Wb[(size_t)(slice * 16 + t) * HH + k];
  const float bias2 = bb[k];

  // ---- per-block constant: c_xi[k] = sum_d xi[d]*(Wa[d][k]-Wa[64+d][k]) + ba[k]
  {
    float p = 0.0f;
#pragma unroll
    for (int t = 0; t < 16; ++t) {
      int d = slice * 16 + t;
      p = fmaf(s_xi[d], Wa[(size_t)d * HH + k] - Wa[(size_t)(64 + d) * HH + k], p);
    }
    p += __shfl_down(p, 32);
    p += __shfl_down(p, 16);
    if (lane < 16) s_cxi[k] = p + ba[k];
  }

  // ---- staging roles (fixed per thread): 128 threads load xj (16 f4/edge),
  //      64 threads load e (8 f4/edge) ----
  const bool has_role = tid < 192;
  const bool is_xj = tid < 128;
  const int role_b = is_xj ? (tid >> 4) : ((tid - 128) >> 3);
  const int role_u = is_xj ? (tid & 15) : ((tid - 128) & 7);
  float4 r = make_float4(0.f, 0.f, 0.f, 0.f);

  // prefetch batch 0
  if (has_role) {
    int j = s_j[role_b < cnt_pad ? role_b : 0];
    if (is_xj) r = ((const float4*)(x + (size_t)j * FF))[role_u];
    else       r = ((const float4*)(e + ((size_t)i * NN + j) * DE))[role_u];
  }

  float acc = 0.0f;

  for (int t0 = 0; t0 < cnt_pad; t0 += EB) {
    __syncthreads();  // previous batch fully consumed; LDS free
    if (has_role) {
      float* dst = s_feat + role_b * PD + (is_xj ? role_u * 4 : FF + role_u * 4);
      *(float4*)dst = r;
    }
    // issue next batch's loads (overlap with compute below)
    if (t0 + EB < cnt_pad && has_role) {
      int j = s_j[t0 + EB + role_b];
      if (is_xj) r = ((const float4*)(x + (size_t)j * FF))[role_u];
      else       r = ((const float4*)(e + ((size_t)i * NN + j) * DE))[role_u];
    }
    __syncthreads();  // staging visible (also covers s_cxi on first pass)

    // ---- layer 1: all 8 edges ----
#pragma unroll
    for (int b = 0; b < EB; ++b) {
      const float4* f4 = (const float4*)(s_feat + b * PD + slice * 24);
      float p = 0.0f;
#pragma unroll
      for (int u = 0; u < 6; ++u) {
        float4 f = f4[u];
        p = fmaf(f.x, w1[4 * u + 0], p);
        p = fmaf(f.y, w1[4 * u + 1], p);
        p = fmaf(f.z, w1[4 * u + 2], p);
        p = fmaf(f.w, w1[4 * u + 3], p);
      }
      p += __shfl_down(p, 32);
      p += __shfl_down(p, 16);
      if (lane < 16) s_h1[b * HH + k] = fmaxf(p + s_cxi[k], 0.0f);
    }
    __syncthreads();  // h1 visible to all waves

    // ---- layer 2: all 8 edges ----
#pragma unroll
    for (int b = 0; b < EB; ++b) {
      const float4* h4 = (const float4*)(s_h1 + b * HH + slice * 16);
      float q = 0.0f;
#pragma unroll
      for (int u = 0; u < 4; ++u) {
        float4 h = h4[u];
        q = fmaf(h.x, w2[4 * u + 0], q);
        q = fmaf(h.y, w2[4 * u + 1], q);
        q = fmaf(h.z, w2[4 * u + 2], q);
        q = fmaf(h.w, w2[4 * u + 3], q);
      }
      q += __shfl_down(q, 32);
      q += __shfl_down(q, 16);
      if (lane < 16) acc = fmaf(s_a[t0 + b], fmaxf(q + bias2, 0.0f), acc);
    }
  }

  if (lane < 16) xout[i * HH + k] = acc;
}

// x2[768,64] -> relu(x2 @ W3[64,128] + b3) -> sigmoid(@ W4[128,1] + b4)
__global__ __launch_bounds__(128) void final_kernel(
    const float* __restrict__ x2, const float* __restrict__ W3,
    const float* __restrict__ b3, const float* __restrict__ W4,
    const float* __restrict__ b4, float* __restrict__ out)
{
  const int i = blockIdx.x;
  const int t = threadIdx.x;  // 0..127
  const int lane = t & 63;
  const int wv = t >> 6;
  __shared__ float sx[64];
  __shared__ float s_red[2];
  if (t < 64) sx[t] = x2[i * 64 + t];
  __syncthreads();
  float p = b3[t];
#pragma unroll
  for (int c = 0; c < 64; ++c) p = fmaf(sx[c], W3[c * 128 + t], p);
  p = fmaxf(p, 0.0f);
  float v = p * W4[t];
  v += __shfl_down(v, 32);
  v += __shfl_down(v, 16);
  v += __shfl_down(v, 8);
  v += __shfl_down(v, 4);
  v += __shfl_down(v, 2);
  v += __shfl_down(v, 1);
  if (lane == 0) s_red[wv] = v;
  __syncthreads();
  if (t == 0) {
    float z = s_red[0] + s_red[1] + b4[0];
    out[i] = 1.0f / (1.0f + expf(-z));
  }
}

extern "C" void kernel_launch(void* const* d_in, const int* in_sizes, int n_in,
                              void* d_out, int out_size, void* d_ws, size_t ws_size,
                              hipStream_t stream) {
  const float* A   = (const float*)d_in[0];
  const float* x   = (const float*)d_in[1];
  const float* e   = (const float*)d_in[2];
  const float* W1a = (const float*)d_in[3];
  const float* b1a = (const float*)d_in[4];
  const float* W1b = (const float*)d_in[5];
  const float* b1b = (const float*)d_in[6];
  const float* W2a = (const float*)d_in[7];
  const float* b2a = (const float*)d_in[8];
  const float* W2b = (const float*)d_in[9];
  const float* b2b = (const float*)d_in[10];
  const float* W3  = (const float*)d_in[11];
  const float* b3  = (const float*)d_in[12];
  const float* W4  = (const float*)d_in[13];
  const float* b4  = (const float*)d_in[14];
  float* out = (float*)d_out;

  float* x1 = (float*)d_ws;            // [768,64]
  float* x2 = x1 + NN * HH;            // [768,64]

  edgeconv_kernel<<<NN, 256, 0, stream>>>(A, x,  e, W1a, b1a, W1b, b1b, x1);
  edgeconv_kernel<<<NN, 256, 0, stream>>>(A, x1, e, W2a, b2a, W2b, b2b, x2);
  final_kernel<<<NN, 128, 0, stream>>>(x2, W3, b3, W4, b4, out);
}